// Round 6
// baseline (274.502 us; speedup 1.0000x reference)
//
#include <hip/hip_runtime.h>

// Problem shape (fixed by setup_inputs): B=2, C=4, D=128, H=192, W=192
#define NB 2
#define NC 4
#define NS (128 * 192 * 192)      // spatial voxels per batch = 4718592
#define NTOT (NB * NS)            // 9437184
#define NSQ (NS / 4)              // float4-quads per batch = 1179648
#define EPSF 1e-8f
#define INF_BITS 0x7F800000u

// Geometry: ONE quad per thread. 6 loads, no loop, minimal live registers
// (~24 VGPR data + 13 acc) -> 8 waves/SIMD occupancy bucket, max TLP.
#define TPB 256
#define BPB (NSQ / TPB)            // 4608 blocks per batch
#define BLOCKS (2 * BPB)           // 9216

// Decomposition: loss = -(R0 + sum_{b,j} s_bj*(P_bj - mn_bj*Q_bj)) / NTOT
//   P_bj = sum z_j*(a_j-lse), Q_bj = sum (a_j-lse), R0 = sum (t==0)*(a_0-lse)
// part layout: 16 floats per block: [0..2]=mn [3..5]=mx [6..8]=P [9..11]=Q [12]=R0

__global__ void k_fused(const float* __restrict__ x,
                        const int* __restrict__ tgt,
                        const float* __restrict__ dist,
                        float* __restrict__ part) {
    const int b = (blockIdx.x >= BPB) ? 1 : 0;
    const int bid = blockIdx.x - b * BPB;
    const int q = bid * TPB + threadIdx.x;

    const int4* t4 = (const int4*)tgt + (size_t)b * NSQ;
    const float4* d4 = (const float4*)dist + (size_t)b * NSQ;
    const float4* xb = (const float4*)x + (size_t)b * NC * NSQ;

    // 6 independent 16B loads, all in flight together.
    float4 x0 = xb[q];
    float4 x1 = xb[q + NSQ];
    float4 x2 = xb[q + 2 * NSQ];
    float4 x3 = xb[q + 3 * NSQ];
    int4 t = t4[q];
    float4 d = d4[q];

    float mn1 = __uint_as_float(INF_BITS), mn2 = mn1, mn3 = mn1;
    float mx1 = 0.f, mx2 = 0.f, mx3 = 0.f;
    float P1 = 0.f, P2 = 0.f, P3 = 0.f;
    float Q1 = 0.f, Q2 = 0.f, Q3 = 0.f;
    float R0 = 0.f;

    auto vox = [&](float a0, float a1, float a2, float a3, int tt, float dv) {
        float m = fmaxf(fmaxf(a0, a1), fmaxf(a2, a3));
        float e = __expf(a0 - m) + __expf(a1 - m) + __expf(a2 - m) + __expf(a3 - m);
        float lse = m + __logf(e);
        float z1 = (tt == 1) ? dv : 0.f;
        float z2 = (tt == 2) ? dv : 0.f;
        float z3 = (tt == 3) ? dv : 0.f;
        mn1 = fminf(mn1, z1); mx1 = fmaxf(mx1, z1);
        mn2 = fminf(mn2, z2); mx2 = fmaxf(mx2, z2);
        mn3 = fminf(mn3, z3); mx3 = fmaxf(mx3, z3);
        float l1 = a1 - lse, l2 = a2 - lse, l3 = a3 - lse;
        P1 += z1 * l1; P2 += z2 * l2; P3 += z3 * l3;
        Q1 += l1; Q2 += l2; Q3 += l3;
        R0 += (tt == 0) ? (a0 - lse) : 0.f;
    };

    vox(x0.x, x1.x, x2.x, x3.x, t.x, d.x);
    vox(x0.y, x1.y, x2.y, x3.y, t.y, d.y);
    vox(x0.z, x1.z, x2.z, x3.z, t.z, d.z);
    vox(x0.w, x1.w, x2.w, x3.w, t.w, d.w);

    // wave(64) butterfly over the 13 accumulators
    for (int off = 32; off; off >>= 1) {
        mn1 = fminf(mn1, __shfl_down(mn1, off, 64));
        mn2 = fminf(mn2, __shfl_down(mn2, off, 64));
        mn3 = fminf(mn3, __shfl_down(mn3, off, 64));
        mx1 = fmaxf(mx1, __shfl_down(mx1, off, 64));
        mx2 = fmaxf(mx2, __shfl_down(mx2, off, 64));
        mx3 = fmaxf(mx3, __shfl_down(mx3, off, 64));
        P1 += __shfl_down(P1, off, 64);
        P2 += __shfl_down(P2, off, 64);
        P3 += __shfl_down(P3, off, 64);
        Q1 += __shfl_down(Q1, off, 64);
        Q2 += __shfl_down(Q2, off, 64);
        Q3 += __shfl_down(Q3, off, 64);
        R0 += __shfl_down(R0, off, 64);
    }

    __shared__ float sv[4][13];
    const int wid = threadIdx.x >> 6;
    if ((threadIdx.x & 63) == 0) {
        sv[wid][0] = mn1; sv[wid][1] = mn2; sv[wid][2] = mn3;
        sv[wid][3] = mx1; sv[wid][4] = mx2; sv[wid][5] = mx3;
        sv[wid][6] = P1;  sv[wid][7] = P2;  sv[wid][8] = P3;
        sv[wid][9] = Q1;  sv[wid][10] = Q2; sv[wid][11] = Q3;
        sv[wid][12] = R0;
    }
    __syncthreads();
    const int i = threadIdx.x;
    if (i < 13) {
        float v = sv[0][i];
        if (i < 3)      v = fminf(fminf(v, sv[1][i]), fminf(sv[2][i], sv[3][i]));
        else if (i < 6) v = fmaxf(fmaxf(v, sv[1][i]), fmaxf(sv[2][i], sv[3][i]));
        else            v = v + sv[1][i] + sv[2][i] + sv[3][i];
        part[(size_t)blockIdx.x * 16 + i] = v;   // plain store — NO atomics
    }
}

// 1024 threads (one block) reduce 9216 x 13 partials (590 KB, L2-warm).
// Threads 0..511 own batch-0 rows, 512..1023 batch-1 (wave-pure batches).
__global__ __launch_bounds__(1024, 1)
void k_final(const float* __restrict__ part, float* __restrict__ out) {
    const int t = threadIdx.x;
    const int batch = t >> 9;
    const int lane9 = t & 511;

    float mn[3] = {__uint_as_float(INF_BITS), __uint_as_float(INF_BITS), __uint_as_float(INF_BITS)};
    float mx[3] = {0.f, 0.f, 0.f};
    double P[3] = {0, 0, 0}, Q[3] = {0, 0, 0}, R0 = 0;

#pragma unroll
    for (int k = 0; k < BPB / 512; k++) {   // 9 rows per thread
        const float4* r = (const float4*)(part + (size_t)(batch * BPB + k * 512 + lane9) * 16);
        float4 r0 = r[0];  // mn1 mn2 mn3 mx1
        float4 r1 = r[1];  // mx2 mx3 P1  P2
        float4 r2 = r[2];  // P3  Q1  Q2  Q3
        float4 r3 = r[3];  // R0  -   -   -
        mn[0] = fminf(mn[0], r0.x); mn[1] = fminf(mn[1], r0.y); mn[2] = fminf(mn[2], r0.z);
        mx[0] = fmaxf(mx[0], r0.w); mx[1] = fmaxf(mx[1], r1.x); mx[2] = fmaxf(mx[2], r1.y);
        P[0] += (double)r1.z; P[1] += (double)r1.w; P[2] += (double)r2.x;
        Q[0] += (double)r2.y; Q[1] += (double)r2.z; Q[2] += (double)r2.w;
        R0 += (double)r3.x;
    }

    for (int off = 32; off; off >>= 1) {
#pragma unroll
        for (int j = 0; j < 3; j++) {
            mn[j] = fminf(mn[j], __shfl_down(mn[j], off, 64));
            mx[j] = fmaxf(mx[j], __shfl_down(mx[j], off, 64));
            P[j] += __shfl_down(P[j], off, 64);
            Q[j] += __shfl_down(Q[j], off, 64);
        }
        R0 += __shfl_down(R0, off, 64);
    }

    __shared__ float smn[16][3], smx[16][3];
    __shared__ double sP[16][3], sQ[16][3], sR[16];
    const int wid = t >> 6;   // waves 0..7 = batch 0, waves 8..15 = batch 1
    if ((t & 63) == 0) {
#pragma unroll
        for (int j = 0; j < 3; j++) {
            smn[wid][j] = mn[j]; smx[wid][j] = mx[j];
            sP[wid][j] = P[j];   sQ[wid][j] = Q[j];
        }
        sR[wid] = R0;
    }
    __syncthreads();
    if (t == 0) {
        double acc = 0.0;
#pragma unroll
        for (int b = 0; b < 2; b++) {
            double Pb[3] = {0, 0, 0}, Qb[3] = {0, 0, 0};
            float mnb[3], mxb[3];
#pragma unroll
            for (int j = 0; j < 3; j++) { mnb[j] = __uint_as_float(INF_BITS); mxb[j] = 0.f; }
#pragma unroll
            for (int w = 8 * b; w < 8 * b + 8; w++) {
                acc += sR[w];
#pragma unroll
                for (int j = 0; j < 3; j++) {
                    mnb[j] = fminf(mnb[j], smn[w][j]);
                    mxb[j] = fmaxf(mxb[j], smx[w][j]);
                    Pb[j] += sP[w][j];
                    Qb[j] += sQ[w][j];
                }
            }
#pragma unroll
            for (int j = 0; j < 3; j++) {
                float sf = 1.0f / (mxb[j] + EPSF - mnb[j]);   // mirror reference fp32 scale
                acc += (double)sf * (Pb[j] - (double)mnb[j] * Qb[j]);
            }
        }
        out[0] = (float)(-acc / (double)NTOT);
    }
}

extern "C" void kernel_launch(void* const* d_in, const int* in_sizes, int n_in,
                              void* d_out, int out_size, void* d_ws, size_t ws_size,
                              hipStream_t stream) {
    const float* net = (const float*)d_in[0];   // [B, C, D, H, W] fp32
    const int* tgt = (const int*)d_in[1];       // [B, 1, D, H, W] int
    const float* dist = (const float*)d_in[2];  // [B, D, H, W] fp32
    float* part = (float*)d_ws;                 // 9216 x 16 floats = 590 KB

    k_fused<<<BLOCKS, TPB, 0, stream>>>(net, tgt, dist, part);
    k_final<<<1, 1024, 0, stream>>>(part, (float*)d_out);
}

// Round 7
// 271.011 us; speedup vs baseline: 1.0129x; 1.0129x over previous
//
#include <hip/hip_runtime.h>

// Problem shape (fixed by setup_inputs): B=2, C=4, D=128, H=192, W=192
#define NB 2
#define NC 4
#define NS (128 * 192 * 192)      // spatial voxels per batch = 4718592
#define NTOT (NB * NS)            // 9437184
#define NSQ (NS / 4)              // float4-quads per batch = 1179648
#define EPSF 1e-8f
#define INF_BITS 0x7F800000u

// Persistent geometry: 1024 blocks = 4 blocks/CU = 16 waves/CU (== the
// waves_per_eu(.,4) residency cap) -> single dispatch round, tails amortized
// over 36 voxels/thread.
#define TPB 256
#define BPB 512                    // blocks per batch
#define BLOCKS (2 * BPB)           // 1024
#define STRIDE (BPB * TPB)         // 131072 quads per sweep
#define ITERS (NSQ / STRIDE)       // exactly 9

// Decomposition: loss = -(R0 + sum_{b,j} s_bj*(P_bj - mn_bj*Q_bj)) / NTOT
//   P_bj = sum z_j*(a_j-lse), Q_bj = sum (a_j-lse), R0 = sum (t==0)*(a_0-lse)
// part layout: 16 floats per block: [0..2]=mn [3..5]=mx [6..8]=P [9..11]=Q [12]=R0

// waves_per_eu(2,4): max=4 stops the allocator register-starving the kernel
// to chase 8 waves/EU (R6: VGPR=20, serialized loads); min=2 keeps the
// budget at 256 so it never force-spills (R4: 44 MB scratch traffic).
__global__ __launch_bounds__(TPB)
__attribute__((amdgpu_waves_per_eu(2, 4)))
void k_fused(const float* __restrict__ x,
             const int* __restrict__ tgt,
             const float* __restrict__ dist,
             float* __restrict__ part) {
    const int b = (blockIdx.x >= BPB) ? 1 : 0;
    const int bid = blockIdx.x - b * BPB;
    const int q0 = bid * TPB + threadIdx.x;

    const int4* t4 = (const int4*)tgt + (size_t)b * NSQ;
    const float4* d4 = (const float4*)dist + (size_t)b * NSQ;
    const float4* xb = (const float4*)x + (size_t)b * NC * NSQ;

    float mn1 = __uint_as_float(INF_BITS), mn2 = mn1, mn3 = mn1;
    float mx1 = 0.f, mx2 = 0.f, mx3 = 0.f;
    float P1 = 0.f, P2 = 0.f, P3 = 0.f;
    float Q1 = 0.f, Q2 = 0.f, Q3 = 0.f;
    float R0 = 0.f;

    auto vox = [&](float a0, float a1, float a2, float a3, int tt, float dv) {
        float m = fmaxf(fmaxf(a0, a1), fmaxf(a2, a3));
        float e = __expf(a0 - m) + __expf(a1 - m) + __expf(a2 - m) + __expf(a3 - m);
        float lse = m + __logf(e);
        float z1 = (tt == 1) ? dv : 0.f;
        float z2 = (tt == 2) ? dv : 0.f;
        float z3 = (tt == 3) ? dv : 0.f;
        mn1 = fminf(mn1, z1); mx1 = fmaxf(mx1, z1);
        mn2 = fminf(mn2, z2); mx2 = fmaxf(mx2, z2);
        mn3 = fminf(mn3, z3); mx3 = fmaxf(mx3, z3);
        float l1 = a1 - lse, l2 = a2 - lse, l3 = a3 - lse;
        P1 += z1 * l1; P2 += z2 * l2; P3 += z3 * l3;
        Q1 += l1; Q2 += l2; Q3 += l3;
        R0 += (tt == 0) ? (a0 - lse) : 0.f;
    };

    // Rotating-register software pipeline: iteration i computes on regs
    // loaded at i-1 while i+1's 6 loads are in flight (~12 loads / 48 data
    // VGPRs live in steady state).
    float4 cx0 = xb[q0];
    float4 cx1 = xb[q0 + NSQ];
    float4 cx2 = xb[q0 + 2 * NSQ];
    float4 cx3 = xb[q0 + 3 * NSQ];
    int4 ct = t4[q0];
    float4 cd = d4[q0];

#pragma unroll 1
    for (int i = 0; i < ITERS; i++) {
        float4 nx0, nx1, nx2, nx3, nd;
        int4 nt;
        if (i + 1 < ITERS) {
            const int qn = q0 + (i + 1) * STRIDE;
            nx0 = xb[qn];
            nx1 = xb[qn + NSQ];
            nx2 = xb[qn + 2 * NSQ];
            nx3 = xb[qn + 3 * NSQ];
            nt = t4[qn];
            nd = d4[qn];
        }
        vox(cx0.x, cx1.x, cx2.x, cx3.x, ct.x, cd.x);
        vox(cx0.y, cx1.y, cx2.y, cx3.y, ct.y, cd.y);
        vox(cx0.z, cx1.z, cx2.z, cx3.z, ct.z, cd.z);
        vox(cx0.w, cx1.w, cx2.w, cx3.w, ct.w, cd.w);
        if (i + 1 < ITERS) {
            cx0 = nx0; cx1 = nx1; cx2 = nx2; cx3 = nx3; ct = nt; cd = nd;
        }
    }

    // wave(64) butterfly over the 13 accumulators
    for (int off = 32; off; off >>= 1) {
        mn1 = fminf(mn1, __shfl_down(mn1, off, 64));
        mn2 = fminf(mn2, __shfl_down(mn2, off, 64));
        mn3 = fminf(mn3, __shfl_down(mn3, off, 64));
        mx1 = fmaxf(mx1, __shfl_down(mx1, off, 64));
        mx2 = fmaxf(mx2, __shfl_down(mx2, off, 64));
        mx3 = fmaxf(mx3, __shfl_down(mx3, off, 64));
        P1 += __shfl_down(P1, off, 64);
        P2 += __shfl_down(P2, off, 64);
        P3 += __shfl_down(P3, off, 64);
        Q1 += __shfl_down(Q1, off, 64);
        Q2 += __shfl_down(Q2, off, 64);
        Q3 += __shfl_down(Q3, off, 64);
        R0 += __shfl_down(R0, off, 64);
    }

    __shared__ float sv[4][13];
    const int wid = threadIdx.x >> 6;
    if ((threadIdx.x & 63) == 0) {
        sv[wid][0] = mn1; sv[wid][1] = mn2; sv[wid][2] = mn3;
        sv[wid][3] = mx1; sv[wid][4] = mx2; sv[wid][5] = mx3;
        sv[wid][6] = P1;  sv[wid][7] = P2;  sv[wid][8] = P3;
        sv[wid][9] = Q1;  sv[wid][10] = Q2; sv[wid][11] = Q3;
        sv[wid][12] = R0;
    }
    __syncthreads();
    const int i = threadIdx.x;
    if (i < 13) {
        float v = sv[0][i];
        if (i < 3)      v = fminf(fminf(v, sv[1][i]), fminf(sv[2][i], sv[3][i]));
        else if (i < 6) v = fmaxf(fmaxf(v, sv[1][i]), fmaxf(sv[2][i], sv[3][i]));
        else            v = v + sv[1][i] + sv[2][i] + sv[3][i];
        part[(size_t)blockIdx.x * 16 + i] = v;   // plain store — NO atomics
    }
}

// 1024 threads, 1 block: thread t reads partial row t (rows 0..511 = batch 0).
__global__ __launch_bounds__(1024, 1)
void k_final(const float* __restrict__ part, float* __restrict__ out) {
    const int t = threadIdx.x;

    const float4* r = (const float4*)(part + (size_t)t * 16);
    float4 r0 = r[0];  // mn1 mn2 mn3 mx1
    float4 r1 = r[1];  // mx2 mx3 P1  P2
    float4 r2 = r[2];  // P3  Q1  Q2  Q3
    float4 r3 = r[3];  // R0  -   -   -
    float mn[3] = {r0.x, r0.y, r0.z};
    float mx[3] = {r0.w, r1.x, r1.y};
    double P[3] = {(double)r1.z, (double)r1.w, (double)r2.x};
    double Q[3] = {(double)r2.y, (double)r2.z, (double)r2.w};
    double R0 = (double)r3.x;

    for (int off = 32; off; off >>= 1) {
#pragma unroll
        for (int j = 0; j < 3; j++) {
            mn[j] = fminf(mn[j], __shfl_down(mn[j], off, 64));
            mx[j] = fmaxf(mx[j], __shfl_down(mx[j], off, 64));
            P[j] += __shfl_down(P[j], off, 64);
            Q[j] += __shfl_down(Q[j], off, 64);
        }
        R0 += __shfl_down(R0, off, 64);
    }

    __shared__ float smn[16][3], smx[16][3];
    __shared__ double sP[16][3], sQ[16][3], sR[16];
    const int wid = t >> 6;   // waves 0..7 = batch 0, waves 8..15 = batch 1
    if ((t & 63) == 0) {
#pragma unroll
        for (int j = 0; j < 3; j++) {
            smn[wid][j] = mn[j]; smx[wid][j] = mx[j];
            sP[wid][j] = P[j];   sQ[wid][j] = Q[j];
        }
        sR[wid] = R0;
    }
    __syncthreads();
    if (t == 0) {
        double acc = 0.0;
#pragma unroll
        for (int b = 0; b < 2; b++) {
            double Pb[3] = {0, 0, 0}, Qb[3] = {0, 0, 0};
            float mnb[3], mxb[3];
#pragma unroll
            for (int j = 0; j < 3; j++) { mnb[j] = __uint_as_float(INF_BITS); mxb[j] = 0.f; }
#pragma unroll
            for (int w = 8 * b; w < 8 * b + 8; w++) {
                acc += sR[w];
#pragma unroll
                for (int j = 0; j < 3; j++) {
                    mnb[j] = fminf(mnb[j], smn[w][j]);
                    mxb[j] = fmaxf(mxb[j], smx[w][j]);
                    Pb[j] += sP[w][j];
                    Qb[j] += sQ[w][j];
                }
            }
#pragma unroll
            for (int j = 0; j < 3; j++) {
                float sf = 1.0f / (mxb[j] + EPSF - mnb[j]);   // mirror reference fp32 scale
                acc += (double)sf * (Pb[j] - (double)mnb[j] * Qb[j]);
            }
        }
        out[0] = (float)(-acc / (double)NTOT);
    }
}

extern "C" void kernel_launch(void* const* d_in, const int* in_sizes, int n_in,
                              void* d_out, int out_size, void* d_ws, size_t ws_size,
                              hipStream_t stream) {
    const float* net = (const float*)d_in[0];   // [B, C, D, H, W] fp32
    const int* tgt = (const int*)d_in[1];       // [B, 1, D, H, W] int
    const float* dist = (const float*)d_in[2];  // [B, D, H, W] fp32
    float* part = (float*)d_ws;                 // 1024 x 16 floats = 64 KB

    k_fused<<<BLOCKS, TPB, 0, stream>>>(net, tgt, dist, part);
    k_final<<<1, 1024, 0, stream>>>(part, (float*)d_out);
}

// Round 8
// 266.926 us; speedup vs baseline: 1.0284x; 1.0153x over previous
//
#include <hip/hip_runtime.h>
#include <stdint.h>

// Problem shape (fixed by setup_inputs): B=2, C=4, D=128, H=192, W=192
#define NB 2
#define NS (128 * 192 * 192)      // spatial voxels per batch = 4718592
#define NTOT (NB * NS)            // 9437184
#define NSQ (NS / 4)              // float4-quads per batch = 1179648
#define EPSF 1e-8f
#define INF_BITS 0x7F800000u

#define TPB 256
#define BPB 1152                   // blocks per batch
#define BLOCKS (2 * BPB)           // 2304
#define STRIDE (BPB * TPB)         // 294912 quads per sweep
#define ITERS (NSQ / STRIDE)       // exactly 4

// Decomposition: loss = -(R0 + sum_{b,j} s_bj*(P_bj - mn_bj*Q_bj)) / NTOT
//   P_bj = sum z_j*(a_j-lse), Q_bj = sum (a_j-lse), R0 = sum (t==0)*(a_0-lse)
// part layout: 16 floats per block: [0..2]=mn [3..5]=mx [6..8]=P [9..11]=Q [12]=R0

typedef __attribute__((address_space(3))) void lds_vp;
typedef const __attribute__((address_space(1))) void glb_vp;

// Async global->LDS DMA, 16B per lane. LDS dest is wave-uniform base;
// HW scatters lane i to base + i*16 (guide §5 caveat).
__device__ __forceinline__ void dma16(void* lds_base, const void* gptr) {
    __builtin_amdgcn_global_load_lds((glb_vp*)gptr, (lds_vp*)lds_base, 16, 0, 0);
}

__global__ __launch_bounds__(TPB)
void k_fused(const float* __restrict__ x,
             const int* __restrict__ tgt,
             const float* __restrict__ dist,
             float* __restrict__ part) {
    // Staging: 2 parities x (4 x-channels + tgt + dist) x 256 threads x 16B = 48 KB
    __shared__ float4 sx[2][4][TPB];
    __shared__ int4   st[2][TPB];
    __shared__ float4 sd[2][TPB];

    const int b = (blockIdx.x >= BPB) ? 1 : 0;
    const int bid = blockIdx.x - b * BPB;
    const int tid = threadIdx.x;
    const int wb = (tid >> 6) << 6;      // wave-uniform base index for DMA dest
    const int q0 = bid * TPB + tid;

    const float4* xb = (const float4*)x + (size_t)b * 4 * NSQ;
    const int4*   t4 = (const int4*)tgt + (size_t)b * NSQ;
    const float4* d4 = (const float4*)dist + (size_t)b * NSQ;

    float mn1 = __uint_as_float(INF_BITS), mn2 = mn1, mn3 = mn1;
    float mx1 = 0.f, mx2 = 0.f, mx3 = 0.f;
    float P1 = 0.f, P2 = 0.f, P3 = 0.f;
    float Q1 = 0.f, Q2 = 0.f, Q3 = 0.f;
    float R0 = 0.f;

    auto issue = [&](int p, int i) {
        const int q = q0 + i * STRIDE;
        dma16(&sx[p][0][wb], &xb[q]);
        dma16(&sx[p][1][wb], &xb[q + NSQ]);
        dma16(&sx[p][2][wb], &xb[q + 2 * NSQ]);
        dma16(&sx[p][3][wb], &xb[q + 3 * NSQ]);
        dma16(&st[p][wb], &t4[q]);
        dma16(&sd[p][wb], &d4[q]);
    };

    auto vox = [&](float a0, float a1, float a2, float a3, int tt, float dv) {
        float m = fmaxf(fmaxf(a0, a1), fmaxf(a2, a3));
        float e = __expf(a0 - m) + __expf(a1 - m) + __expf(a2 - m) + __expf(a3 - m);
        float lse = m + __logf(e);
        float z1 = (tt == 1) ? dv : 0.f;
        float z2 = (tt == 2) ? dv : 0.f;
        float z3 = (tt == 3) ? dv : 0.f;
        mn1 = fminf(mn1, z1); mx1 = fmaxf(mx1, z1);
        mn2 = fminf(mn2, z2); mx2 = fmaxf(mx2, z2);
        mn3 = fminf(mn3, z3); mx3 = fmaxf(mx3, z3);
        float l1 = a1 - lse, l2 = a2 - lse, l3 = a3 - lse;
        P1 += z1 * l1; P2 += z2 * l2; P3 += z3 * l3;
        Q1 += l1; Q2 += l2; Q3 += l3;
        R0 += (tt == 0) ? (a0 - lse) : 0.f;
    };

    // Per-wave pipeline, NO intra-loop __syncthreads (each wave consumes only
    // its own staged region): [vmcnt(0)] [ds_read tile p, lgkmcnt(0)]
    // [issue p^1 for i+1 — DMA overlaps vox compute] [vox x4].
    issue(0, 0);
#pragma unroll
    for (int i = 0; i < ITERS; i++) {
        const int p = i & 1;
        asm volatile("s_waitcnt vmcnt(0)" ::: "memory");   // tile p DMA complete
        float4 x0 = sx[p][0][tid];
        float4 x1 = sx[p][1][tid];
        float4 x2 = sx[p][2][tid];
        float4 x3 = sx[p][3][tid];
        int4   t  = st[p][tid];
        float4 d  = sd[p][tid];
        asm volatile("s_waitcnt lgkmcnt(0)" ::: "memory"); // reads retired before p^1.. reuse
        if (i + 1 < ITERS) issue(p ^ 1, i + 1);            // overlap DMA with compute
        vox(x0.x, x1.x, x2.x, x3.x, t.x, d.x);
        vox(x0.y, x1.y, x2.y, x3.y, t.y, d.y);
        vox(x0.z, x1.z, x2.z, x3.z, t.z, d.z);
        vox(x0.w, x1.w, x2.w, x3.w, t.w, d.w);
    }

    // wave(64) butterfly over the 13 accumulators
    for (int off = 32; off; off >>= 1) {
        mn1 = fminf(mn1, __shfl_down(mn1, off, 64));
        mn2 = fminf(mn2, __shfl_down(mn2, off, 64));
        mn3 = fminf(mn3, __shfl_down(mn3, off, 64));
        mx1 = fmaxf(mx1, __shfl_down(mx1, off, 64));
        mx2 = fmaxf(mx2, __shfl_down(mx2, off, 64));
        mx3 = fmaxf(mx3, __shfl_down(mx3, off, 64));
        P1 += __shfl_down(P1, off, 64);
        P2 += __shfl_down(P2, off, 64);
        P3 += __shfl_down(P3, off, 64);
        Q1 += __shfl_down(Q1, off, 64);
        Q2 += __shfl_down(Q2, off, 64);
        Q3 += __shfl_down(Q3, off, 64);
        R0 += __shfl_down(R0, off, 64);
    }

    __shared__ float sv[4][13];
    const int wid = tid >> 6;
    if ((tid & 63) == 0) {
        sv[wid][0] = mn1; sv[wid][1] = mn2; sv[wid][2] = mn3;
        sv[wid][3] = mx1; sv[wid][4] = mx2; sv[wid][5] = mx3;
        sv[wid][6] = P1;  sv[wid][7] = P2;  sv[wid][8] = P3;
        sv[wid][9] = Q1;  sv[wid][10] = Q2; sv[wid][11] = Q3;
        sv[wid][12] = R0;
    }
    __syncthreads();
    if (tid < 13) {
        float v = sv[0][tid];
        if (tid < 3)      v = fminf(fminf(v, sv[1][tid]), fminf(sv[2][tid], sv[3][tid]));
        else if (tid < 6) v = fmaxf(fmaxf(v, sv[1][tid]), fmaxf(sv[2][tid], sv[3][tid]));
        else              v = v + sv[1][tid] + sv[2][tid] + sv[3][tid];
        part[(size_t)blockIdx.x * 16 + tid] = v;   // plain store — NO atomics
    }
}

// One block (256 thr) reduces 2304 x 13 partials. Threads 0..127 = batch 0
// rows, 128..255 = batch 1 (wave-pure batches), 9 rows per thread.
__global__ __launch_bounds__(256, 1)
void k_final(const float* __restrict__ part, float* __restrict__ out) {
    const int t = threadIdx.x;
    const int batch = t >> 7;
    const int lane7 = t & 127;

    float mn[3] = {__uint_as_float(INF_BITS), __uint_as_float(INF_BITS), __uint_as_float(INF_BITS)};
    float mx[3] = {0.f, 0.f, 0.f};
    double P[3] = {0, 0, 0}, Q[3] = {0, 0, 0}, R0 = 0;

#pragma unroll
    for (int k = 0; k < BPB / 128; k++) {   // 9 rows per thread
        const float4* r = (const float4*)(part + (size_t)(batch * BPB + k * 128 + lane7) * 16);
        float4 r0 = r[0];  // mn1 mn2 mn3 mx1
        float4 r1 = r[1];  // mx2 mx3 P1  P2
        float4 r2 = r[2];  // P3  Q1  Q2  Q3
        float4 r3 = r[3];  // R0  -   -   -
        mn[0] = fminf(mn[0], r0.x); mn[1] = fminf(mn[1], r0.y); mn[2] = fminf(mn[2], r0.z);
        mx[0] = fmaxf(mx[0], r0.w); mx[1] = fmaxf(mx[1], r1.x); mx[2] = fmaxf(mx[2], r1.y);
        P[0] += (double)r1.z; P[1] += (double)r1.w; P[2] += (double)r2.x;
        Q[0] += (double)r2.y; Q[1] += (double)r2.z; Q[2] += (double)r2.w;
        R0 += (double)r3.x;
    }

    for (int off = 32; off; off >>= 1) {
#pragma unroll
        for (int j = 0; j < 3; j++) {
            mn[j] = fminf(mn[j], __shfl_down(mn[j], off, 64));
            mx[j] = fmaxf(mx[j], __shfl_down(mx[j], off, 64));
            P[j] += __shfl_down(P[j], off, 64);
            Q[j] += __shfl_down(Q[j], off, 64);
        }
        R0 += __shfl_down(R0, off, 64);
    }

    __shared__ float smn[4][3], smx[4][3];
    __shared__ double sP[4][3], sQ[4][3], sR[4];
    const int wid = t >> 6;
    if ((t & 63) == 0) {
#pragma unroll
        for (int j = 0; j < 3; j++) {
            smn[wid][j] = mn[j]; smx[wid][j] = mx[j];
            sP[wid][j] = P[j];   sQ[wid][j] = Q[j];
        }
        sR[wid] = R0;
    }
    __syncthreads();
    if (t == 0) {
        double acc = 0.0;
#pragma unroll
        for (int b = 0; b < 2; b++) {
            const int w0 = 2 * b, w1 = 2 * b + 1;
            acc += sR[w0] + sR[w1];
#pragma unroll
            for (int j = 0; j < 3; j++) {
                float mnf = fminf(smn[w0][j], smn[w1][j]);
                float mxf = fmaxf(smx[w0][j], smx[w1][j]);
                float sf = 1.0f / (mxf + EPSF - mnf);   // mirror reference fp32 scale
                acc += (double)sf * ((sP[w0][j] + sP[w1][j]) - (double)mnf * (sQ[w0][j] + sQ[w1][j]));
            }
        }
        out[0] = (float)(-acc / (double)NTOT);
    }
}

extern "C" void kernel_launch(void* const* d_in, const int* in_sizes, int n_in,
                              void* d_out, int out_size, void* d_ws, size_t ws_size,
                              hipStream_t stream) {
    const float* net = (const float*)d_in[0];   // [B, C, D, H, W] fp32
    const int* tgt = (const int*)d_in[1];       // [B, 1, D, H, W] int
    const float* dist = (const float*)d_in[2];  // [B, D, H, W] fp32
    float* part = (float*)d_ws;                 // 2304 x 16 floats = 147 KB

    k_fused<<<BLOCKS, TPB, 0, stream>>>(net, tgt, dist, part);
    k_final<<<1, 256, 0, stream>>>(part, (float*)d_out);
}

// Round 9
// 251.806 us; speedup vs baseline: 1.0901x; 1.0600x over previous
//
#include <hip/hip_runtime.h>

// Problem shape (fixed by setup_inputs): B=2, C=4, D=128, H=192, W=192
#define NB 2
#define NS (128 * 192 * 192)      // spatial voxels per batch = 4718592
#define NTOT (NB * NS)            // 9437184
#define NSQ (NS / 4)              // float4-quads per batch = 1179648
#define EPSF 1e-8f
#define INF_BITS 0x7F800000u

// Persistent geometry (R7): 1024 blocks = 4/CU, 9 pipelined iterations.
#define TPB 256
#define BPB 512                    // blocks per batch
#define BLOCKS (2 * BPB)           // 1024
#define STRIDE (BPB * TPB)         // 131072 quads per sweep
#define ITERS (NSQ / STRIDE)       // exactly 9

// Decomposition: loss = -(R0 + sum_{b,j} s_bj*(P_bj - mn_bj*Q_bj)) / NTOT
//   P_bj = sum z_j*(a_j-lse), Q_bj = sum (a_j-lse), R0 = sum (t==0)*(a_0-lse)
// part layout: 16 floats per block: [0..2]=mn [3..5]=mx [6..8]=P [9..11]=Q [12]=R0

// Vector types compatible with __builtin_nontemporal_load
typedef float __attribute__((ext_vector_type(4))) f32x4;
typedef int   __attribute__((ext_vector_type(4))) i32x4;

__device__ __forceinline__ f32x4 ldnt_f4(const float* p) {
    return __builtin_nontemporal_load((const f32x4*)p);
}
__device__ __forceinline__ i32x4 ldnt_i4(const int* p) {
    return __builtin_nontemporal_load((const i32x4*)p);
}

__global__ __launch_bounds__(TPB)
__attribute__((amdgpu_waves_per_eu(2, 4)))
void k_fused(const float* __restrict__ x,
             const int* __restrict__ tgt,
             const float* __restrict__ dist,
             float* __restrict__ part) {
    const int b = (blockIdx.x >= BPB) ? 1 : 0;
    const int bid = blockIdx.x - b * BPB;
    const int q0 = bid * TPB + threadIdx.x;

    const float* xb = x + (size_t)b * 4 * NSQ * 4;   // batch base (floats)
    const int*   tb = tgt + (size_t)b * NSQ * 4;
    const float* db = dist + (size_t)b * NSQ * 4;

    float mn1 = __uint_as_float(INF_BITS), mn2 = mn1, mn3 = mn1;
    float mx1 = 0.f, mx2 = 0.f, mx3 = 0.f;
    float P1 = 0.f, P2 = 0.f, P3 = 0.f;
    float Q1 = 0.f, Q2 = 0.f, Q3 = 0.f;
    float R0 = 0.f;

    auto vox = [&](float a0, float a1, float a2, float a3, int tt, float dv) {
        float m = fmaxf(fmaxf(a0, a1), fmaxf(a2, a3));
        float e = __expf(a0 - m) + __expf(a1 - m) + __expf(a2 - m) + __expf(a3 - m);
        float lse = m + __logf(e);
        float z1 = (tt == 1) ? dv : 0.f;
        float z2 = (tt == 2) ? dv : 0.f;
        float z3 = (tt == 3) ? dv : 0.f;
        mn1 = fminf(mn1, z1); mx1 = fmaxf(mx1, z1);
        mn2 = fminf(mn2, z2); mx2 = fmaxf(mx2, z2);
        mn3 = fminf(mn3, z3); mx3 = fmaxf(mx3, z3);
        float l1 = a1 - lse, l2 = a2 - lse, l3 = a3 - lse;
        P1 += z1 * l1; P2 += z2 * l2; P3 += z3 * l3;
        Q1 += l1; Q2 += l2; Q3 += l3;
        R0 += (tt == 0) ? (a0 - lse) : 0.f;
    };

    // Rotating-register pipeline (R7) with NON-TEMPORAL streamed loads:
    // nt loads don't allocate in the vector L1, sidestepping the 4KB-period
    // set aliasing of the six streams (all at multiples of 0x1200000).
    f32x4 cx0 = ldnt_f4(xb + (size_t)q0 * 4);
    f32x4 cx1 = ldnt_f4(xb + (size_t)(q0 + NSQ) * 4);
    f32x4 cx2 = ldnt_f4(xb + (size_t)(q0 + 2 * NSQ) * 4);
    f32x4 cx3 = ldnt_f4(xb + (size_t)(q0 + 3 * NSQ) * 4);
    i32x4 ct  = ldnt_i4(tb + (size_t)q0 * 4);
    f32x4 cd  = ldnt_f4(db + (size_t)q0 * 4);

#pragma unroll 1
    for (int i = 0; i < ITERS; i++) {
        f32x4 nx0, nx1, nx2, nx3, nd;
        i32x4 nt;
        if (i + 1 < ITERS) {
            const int qn = q0 + (i + 1) * STRIDE;
            nx0 = ldnt_f4(xb + (size_t)qn * 4);
            nx1 = ldnt_f4(xb + (size_t)(qn + NSQ) * 4);
            nx2 = ldnt_f4(xb + (size_t)(qn + 2 * NSQ) * 4);
            nx3 = ldnt_f4(xb + (size_t)(qn + 3 * NSQ) * 4);
            nt  = ldnt_i4(tb + (size_t)qn * 4);
            nd  = ldnt_f4(db + (size_t)qn * 4);
        }
        vox(cx0.x, cx1.x, cx2.x, cx3.x, ct.x, cd.x);
        vox(cx0.y, cx1.y, cx2.y, cx3.y, ct.y, cd.y);
        vox(cx0.z, cx1.z, cx2.z, cx3.z, ct.z, cd.z);
        vox(cx0.w, cx1.w, cx2.w, cx3.w, ct.w, cd.w);
        if (i + 1 < ITERS) {
            cx0 = nx0; cx1 = nx1; cx2 = nx2; cx3 = nx3; ct = nt; cd = nd;
        }
    }

    // wave(64) butterfly over the 13 accumulators
    for (int off = 32; off; off >>= 1) {
        mn1 = fminf(mn1, __shfl_down(mn1, off, 64));
        mn2 = fminf(mn2, __shfl_down(mn2, off, 64));
        mn3 = fminf(mn3, __shfl_down(mn3, off, 64));
        mx1 = fmaxf(mx1, __shfl_down(mx1, off, 64));
        mx2 = fmaxf(mx2, __shfl_down(mx2, off, 64));
        mx3 = fmaxf(mx3, __shfl_down(mx3, off, 64));
        P1 += __shfl_down(P1, off, 64);
        P2 += __shfl_down(P2, off, 64);
        P3 += __shfl_down(P3, off, 64);
        Q1 += __shfl_down(Q1, off, 64);
        Q2 += __shfl_down(Q2, off, 64);
        Q3 += __shfl_down(Q3, off, 64);
        R0 += __shfl_down(R0, off, 64);
    }

    __shared__ float sv[4][13];
    const int wid = threadIdx.x >> 6;
    if ((threadIdx.x & 63) == 0) {
        sv[wid][0] = mn1; sv[wid][1] = mn2; sv[wid][2] = mn3;
        sv[wid][3] = mx1; sv[wid][4] = mx2; sv[wid][5] = mx3;
        sv[wid][6] = P1;  sv[wid][7] = P2;  sv[wid][8] = P3;
        sv[wid][9] = Q1;  sv[wid][10] = Q2; sv[wid][11] = Q3;
        sv[wid][12] = R0;
    }
    __syncthreads();
    const int i = threadIdx.x;
    if (i < 13) {
        float v = sv[0][i];
        if (i < 3)      v = fminf(fminf(v, sv[1][i]), fminf(sv[2][i], sv[3][i]));
        else if (i < 6) v = fmaxf(fmaxf(v, sv[1][i]), fmaxf(sv[2][i], sv[3][i]));
        else            v = v + sv[1][i] + sv[2][i] + sv[3][i];
        part[(size_t)blockIdx.x * 16 + i] = v;   // plain store — NO atomics
    }
}

// 1024 threads, 1 block: thread t reads partial row t (rows 0..511 = batch 0).
__global__ __launch_bounds__(1024, 1)
void k_final(const float* __restrict__ part, float* __restrict__ out) {
    const int t = threadIdx.x;

    const float4* r = (const float4*)(part + (size_t)t * 16);
    float4 r0 = r[0];  // mn1 mn2 mn3 mx1
    float4 r1 = r[1];  // mx2 mx3 P1  P2
    float4 r2 = r[2];  // P3  Q1  Q2  Q3
    float4 r3 = r[3];  // R0  -   -   -
    float mn[3] = {r0.x, r0.y, r0.z};
    float mx[3] = {r0.w, r1.x, r1.y};
    double P[3] = {(double)r1.z, (double)r1.w, (double)r2.x};
    double Q[3] = {(double)r2.y, (double)r2.z, (double)r2.w};
    double R0 = (double)r3.x;

    for (int off = 32; off; off >>= 1) {
#pragma unroll
        for (int j = 0; j < 3; j++) {
            mn[j] = fminf(mn[j], __shfl_down(mn[j], off, 64));
            mx[j] = fmaxf(mx[j], __shfl_down(mx[j], off, 64));
            P[j] += __shfl_down(P[j], off, 64);
            Q[j] += __shfl_down(Q[j], off, 64);
        }
        R0 += __shfl_down(R0, off, 64);
    }

    __shared__ float smn[16][3], smx[16][3];
    __shared__ double sP[16][3], sQ[16][3], sR[16];
    const int wid = t >> 6;   // waves 0..7 = batch 0, waves 8..15 = batch 1
    if ((t & 63) == 0) {
#pragma unroll
        for (int j = 0; j < 3; j++) {
            smn[wid][j] = mn[j]; smx[wid][j] = mx[j];
            sP[wid][j] = P[j];   sQ[wid][j] = Q[j];
        }
        sR[wid] = R0;
    }
    __syncthreads();
    if (t == 0) {
        double acc = 0.0;
#pragma unroll
        for (int b = 0; b < 2; b++) {
            double Pb[3] = {0, 0, 0}, Qb[3] = {0, 0, 0};
            float mnb[3], mxb[3];
#pragma unroll
            for (int j = 0; j < 3; j++) { mnb[j] = __uint_as_float(INF_BITS); mxb[j] = 0.f; }
#pragma unroll
            for (int w = 8 * b; w < 8 * b + 8; w++) {
                acc += sR[w];
#pragma unroll
                for (int j = 0; j < 3; j++) {
                    mnb[j] = fminf(mnb[j], smn[w][j]);
                    mxb[j] = fmaxf(mxb[j], smx[w][j]);
                    Pb[j] += sP[w][j];
                    Qb[j] += sQ[w][j];
                }
            }
#pragma unroll
            for (int j = 0; j < 3; j++) {
                float sf = 1.0f / (mxb[j] + EPSF - mnb[j]);   // mirror reference fp32 scale
                acc += (double)sf * (Pb[j] - (double)mnb[j] * Qb[j]);
            }
        }
        out[0] = (float)(-acc / (double)NTOT);
    }
}

extern "C" void kernel_launch(void* const* d_in, const int* in_sizes, int n_in,
                              void* d_out, int out_size, void* d_ws, size_t ws_size,
                              hipStream_t stream) {
    const float* net = (const float*)d_in[0];   // [B, C, D, H, W] fp32
    const int* tgt = (const int*)d_in[1];       // [B, 1, D, H, W] int
    const float* dist = (const float*)d_in[2];  // [B, D, H, W] fp32
    float* part = (float*)d_ws;                 // 1024 x 16 floats = 64 KB

    k_fused<<<BLOCKS, TPB, 0, stream>>>(net, tgt, dist, part);
    k_final<<<1, 1024, 0, stream>>>(part, (float*)d_out);
}

// Round 10
// 249.065 us; speedup vs baseline: 1.1021x; 1.0110x over previous
//
#include <hip/hip_runtime.h>

// Problem shape (fixed by setup_inputs): B=2, C=4, D=128, H=192, W=192
#define NB 2
#define NS (128 * 192 * 192)      // spatial voxels per batch = 4718592
#define NTOT (NB * NS)            // 9437184
#define NSQ (NS / 4)              // float4-quads per batch = 1179648
#define EPSF 1e-8f
#define INF_BITS 0x7F800000u

// Geometry: 1536 blocks = 6 blocks/CU = 24 waves/CU (matches waves_per_eu max=6).
#define TPB 256
#define BPB 768                    // blocks per batch
#define BLOCKS (2 * BPB)           // 1536
#define STRIDE (BPB * TPB)         // 196608 quads per sweep
#define ITERS (NSQ / STRIDE)       // exactly 6

// Decomposition: loss = -(R0 + sum_{b,j} s_bj*(P_bj - mn_bj*Q_bj)) / NTOT
//   P_bj = sum z_j*(a_j-lse), Q_bj = sum (a_j-lse), R0 = sum (t==0)*(a_0-lse)
// part layout: 16 floats per block: [0..2]=mn [3..5]=mx [6..8]=P [9..11]=Q [12]=R0

typedef float __attribute__((ext_vector_type(4))) f32x4;
typedef int   __attribute__((ext_vector_type(4))) i32x4;

__device__ __forceinline__ f32x4 ldnt_f4(const float* p) {
    return __builtin_nontemporal_load((const f32x4*)p);
}
__device__ __forceinline__ i32x4 ldnt_i4(const int* p) {
    return __builtin_nontemporal_load((const i32x4*)p);
}

// waves_per_eu(2,6): max=6 -> VGPR budget ~84 (pipeline needs ~56, fits; keeps
// the allocator from register-starving as in R6), 1.5x the TLP of R9's (2,4).
__global__ __launch_bounds__(TPB)
__attribute__((amdgpu_waves_per_eu(2, 6)))
void k_fused(const float* __restrict__ x,
             const int* __restrict__ tgt,
             const float* __restrict__ dist,
             float* __restrict__ part) {
    const int b = (blockIdx.x >= BPB) ? 1 : 0;
    const int bid = blockIdx.x - b * BPB;
    const int q0 = bid * TPB + threadIdx.x;

    const float* xb = x + (size_t)b * 4 * NSQ * 4;   // batch base (floats)
    const int*   tb = tgt + (size_t)b * NSQ * 4;
    const float* db = dist + (size_t)b * NSQ * 4;

    float mn1 = __uint_as_float(INF_BITS), mn2 = mn1, mn3 = mn1;
    float mx1 = 0.f, mx2 = 0.f, mx3 = 0.f;
    float P1 = 0.f, P2 = 0.f, P3 = 0.f;
    float Q1 = 0.f, Q2 = 0.f, Q3 = 0.f;
    float R0 = 0.f;

    auto vox = [&](float a0, float a1, float a2, float a3, int tt, float dv) {
        float m = fmaxf(fmaxf(a0, a1), fmaxf(a2, a3));
        float e = __expf(a0 - m) + __expf(a1 - m) + __expf(a2 - m) + __expf(a3 - m);
        float lse = m + __logf(e);
        float z1 = (tt == 1) ? dv : 0.f;
        float z2 = (tt == 2) ? dv : 0.f;
        float z3 = (tt == 3) ? dv : 0.f;
        mn1 = fminf(mn1, z1); mx1 = fmaxf(mx1, z1);
        mn2 = fminf(mn2, z2); mx2 = fmaxf(mx2, z2);
        mn3 = fminf(mn3, z3); mx3 = fmaxf(mx3, z3);
        float l1 = a1 - lse, l2 = a2 - lse, l3 = a3 - lse;
        P1 += z1 * l1; P2 += z2 * l2; P3 += z3 * l3;
        Q1 += l1; Q2 += l2; Q3 += l3;
        R0 += (tt == 0) ? (a0 - lse) : 0.f;
    };

    // Rotating-register pipeline with non-temporal streamed loads (R9).
    f32x4 cx0 = ldnt_f4(xb + (size_t)q0 * 4);
    f32x4 cx1 = ldnt_f4(xb + (size_t)(q0 + NSQ) * 4);
    f32x4 cx2 = ldnt_f4(xb + (size_t)(q0 + 2 * NSQ) * 4);
    f32x4 cx3 = ldnt_f4(xb + (size_t)(q0 + 3 * NSQ) * 4);
    i32x4 ct  = ldnt_i4(tb + (size_t)q0 * 4);
    f32x4 cd  = ldnt_f4(db + (size_t)q0 * 4);

#pragma unroll 1
    for (int i = 0; i < ITERS; i++) {
        f32x4 nx0, nx1, nx2, nx3, nd;
        i32x4 nt;
        if (i + 1 < ITERS) {
            const int qn = q0 + (i + 1) * STRIDE;
            nx0 = ldnt_f4(xb + (size_t)qn * 4);
            nx1 = ldnt_f4(xb + (size_t)(qn + NSQ) * 4);
            nx2 = ldnt_f4(xb + (size_t)(qn + 2 * NSQ) * 4);
            nx3 = ldnt_f4(xb + (size_t)(qn + 3 * NSQ) * 4);
            nt  = ldnt_i4(tb + (size_t)qn * 4);
            nd  = ldnt_f4(db + (size_t)qn * 4);
        }
        vox(cx0.x, cx1.x, cx2.x, cx3.x, ct.x, cd.x);
        vox(cx0.y, cx1.y, cx2.y, cx3.y, ct.y, cd.y);
        vox(cx0.z, cx1.z, cx2.z, cx3.z, ct.z, cd.z);
        vox(cx0.w, cx1.w, cx2.w, cx3.w, ct.w, cd.w);
        if (i + 1 < ITERS) {
            cx0 = nx0; cx1 = nx1; cx2 = nx2; cx3 = nx3; ct = nt; cd = nd;
        }
    }

    // wave(64) butterfly over the 13 accumulators
    for (int off = 32; off; off >>= 1) {
        mn1 = fminf(mn1, __shfl_down(mn1, off, 64));
        mn2 = fminf(mn2, __shfl_down(mn2, off, 64));
        mn3 = fminf(mn3, __shfl_down(mn3, off, 64));
        mx1 = fmaxf(mx1, __shfl_down(mx1, off, 64));
        mx2 = fmaxf(mx2, __shfl_down(mx2, off, 64));
        mx3 = fmaxf(mx3, __shfl_down(mx3, off, 64));
        P1 += __shfl_down(P1, off, 64);
        P2 += __shfl_down(P2, off, 64);
        P3 += __shfl_down(P3, off, 64);
        Q1 += __shfl_down(Q1, off, 64);
        Q2 += __shfl_down(Q2, off, 64);
        Q3 += __shfl_down(Q3, off, 64);
        R0 += __shfl_down(R0, off, 64);
    }

    __shared__ float sv[4][13];
    const int wid = threadIdx.x >> 6;
    if ((threadIdx.x & 63) == 0) {
        sv[wid][0] = mn1; sv[wid][1] = mn2; sv[wid][2] = mn3;
        sv[wid][3] = mx1; sv[wid][4] = mx2; sv[wid][5] = mx3;
        sv[wid][6] = P1;  sv[wid][7] = P2;  sv[wid][8] = P3;
        sv[wid][9] = Q1;  sv[wid][10] = Q2; sv[wid][11] = Q3;
        sv[wid][12] = R0;
    }
    __syncthreads();
    const int i = threadIdx.x;
    if (i < 13) {
        float v = sv[0][i];
        if (i < 3)      v = fminf(fminf(v, sv[1][i]), fminf(sv[2][i], sv[3][i]));
        else if (i < 6) v = fmaxf(fmaxf(v, sv[1][i]), fmaxf(sv[2][i], sv[3][i]));
        else            v = v + sv[1][i] + sv[2][i] + sv[3][i];
        part[(size_t)blockIdx.x * 16 + i] = v;   // plain store — NO atomics
    }
}

// 512 threads, 1 block: thread t reduces 3 rows of one batch.
// t<256 -> batch 0 rows {lane, lane+256, lane+512}; t>=256 -> batch 1 (+768).
// Waves 0..3 are pure batch-0, waves 4..7 pure batch-1.
__global__ __launch_bounds__(512, 1)
void k_final(const float* __restrict__ part, float* __restrict__ out) {
    const int t = threadIdx.x;
    const int batch = t >> 8;
    const int lane8 = t & 255;

    float mn[3] = {__uint_as_float(INF_BITS), __uint_as_float(INF_BITS), __uint_as_float(INF_BITS)};
    float mx[3] = {0.f, 0.f, 0.f};
    double P[3] = {0, 0, 0}, Q[3] = {0, 0, 0}, R0 = 0;

#pragma unroll
    for (int k = 0; k < 3; k++) {
        const float4* r = (const float4*)(part + (size_t)(batch * BPB + k * 256 + lane8) * 16);
        float4 r0 = r[0];  // mn1 mn2 mn3 mx1
        float4 r1 = r[1];  // mx2 mx3 P1  P2
        float4 r2 = r[2];  // P3  Q1  Q2  Q3
        float4 r3 = r[3];  // R0  -   -   -
        mn[0] = fminf(mn[0], r0.x); mn[1] = fminf(mn[1], r0.y); mn[2] = fminf(mn[2], r0.z);
        mx[0] = fmaxf(mx[0], r0.w); mx[1] = fmaxf(mx[1], r1.x); mx[2] = fmaxf(mx[2], r1.y);
        P[0] += (double)r1.z; P[1] += (double)r1.w; P[2] += (double)r2.x;
        Q[0] += (double)r2.y; Q[1] += (double)r2.z; Q[2] += (double)r2.w;
        R0 += (double)r3.x;
    }

    for (int off = 32; off; off >>= 1) {
#pragma unroll
        for (int j = 0; j < 3; j++) {
            mn[j] = fminf(mn[j], __shfl_down(mn[j], off, 64));
            mx[j] = fmaxf(mx[j], __shfl_down(mx[j], off, 64));
            P[j] += __shfl_down(P[j], off, 64);
            Q[j] += __shfl_down(Q[j], off, 64);
        }
        R0 += __shfl_down(R0, off, 64);
    }

    __shared__ float smn[8][3], smx[8][3];
    __shared__ double sP[8][3], sQ[8][3], sR[8];
    const int wid = t >> 6;   // waves 0..3 = batch 0, waves 4..7 = batch 1
    if ((t & 63) == 0) {
#pragma unroll
        for (int j = 0; j < 3; j++) {
            smn[wid][j] = mn[j]; smx[wid][j] = mx[j];
            sP[wid][j] = P[j];   sQ[wid][j] = Q[j];
        }
        sR[wid] = R0;
    }
    __syncthreads();
    if (t == 0) {
        double acc = 0.0;
#pragma unroll
        for (int b = 0; b < 2; b++) {
            double Pb[3] = {0, 0, 0}, Qb[3] = {0, 0, 0};
            float mnb[3], mxb[3];
#pragma unroll
            for (int j = 0; j < 3; j++) { mnb[j] = __uint_as_float(INF_BITS); mxb[j] = 0.f; }
#pragma unroll
            for (int w = 4 * b; w < 4 * b + 4; w++) {
                acc += sR[w];
#pragma unroll
                for (int j = 0; j < 3; j++) {
                    mnb[j] = fminf(mnb[j], smn[w][j]);
                    mxb[j] = fmaxf(mxb[j], smx[w][j]);
                    Pb[j] += sP[w][j];
                    Qb[j] += sQ[w][j];
                }
            }
#pragma unroll
            for (int j = 0; j < 3; j++) {
                float sf = 1.0f / (mxb[j] + EPSF - mnb[j]);   // mirror reference fp32 scale
                acc += (double)sf * (Pb[j] - (double)mnb[j] * Qb[j]);
            }
        }
        out[0] = (float)(-acc / (double)NTOT);
    }
}

extern "C" void kernel_launch(void* const* d_in, const int* in_sizes, int n_in,
                              void* d_out, int out_size, void* d_ws, size_t ws_size,
                              hipStream_t stream) {
    const float* net = (const float*)d_in[0];   // [B, C, D, H, W] fp32
    const int* tgt = (const int*)d_in[1];       // [B, 1, D, H, W] int
    const float* dist = (const float*)d_in[2];  // [B, D, H, W] fp32
    float* part = (float*)d_ws;                 // 1536 x 16 floats = 98 KB

    k_fused<<<BLOCKS, TPB, 0, stream>>>(net, tgt, dist, part);
    k_final<<<1, 512, 0, stream>>>(part, (float*)d_out);
}